// Round 9
// baseline (246.239 us; speedup 1.0000x reference)
//
#include <hip/hip_runtime.h>
#include <hip/hip_bf16.h>

typedef __hip_bfloat16 bf16;

// R9: dispatch-count round. 5 -> 4 kernels:
//  - setup: prep (WT4/WoF/gammaF/boF/biasWS) + zero segsum/segkv. 145 blocks.
//  - proj: unchanged math; additionally atomicAdd per-segment sum(k), sum(k*v)
//    (scanA eliminated; v_ws dead - v only ever fed k*v).
//  - scanB: 16 x 128: tids 0-63 cumk in place + kvmean; tids 64-127 w_sum.
//  - out: unchanged.
// flags[i]: 0=f32, 1=bf16, 2=all-zero. flags[13] = any bf16 (output dtype).

__device__ __forceinline__ float ldf(const void* p, int f, long idx) {
    if (f == 0) return ((const float*)p)[idx];
    if (f == 1) {
        unsigned int u = ((unsigned int)((const unsigned short*)p)[idx]) << 16;
        float r; __builtin_memcpy(&r, &u, 4); return r;
    }
    return 0.f;
}

__device__ __forceinline__ int sniff_one(const unsigned short* u, int els) {
    int n16 = els < 64 ? els : 64;
    bool allzero = true;
    for (int j = 0; j < n16; ++j) if (u[j] != 0) { allzero = false; break; }
    if (allzero) return 2;
    int npair = n16 / 2;
    for (int j = 0; j < npair; ++j) {
        unsigned short lo = u[2 * j], hi = u[2 * j + 1];
        int elo = (lo >> 7) & 0xFF, ehi = (hi >> 7) & 0xFF;
        bool lo_ok = (elo >= 64 && elo <= 190) || lo == 0;
        bool hi_ok = (ehi >= 64 && ehi <= 190) || hi == 0;
        if (!(lo_ok && hi_ok)) return 0;
    }
    return 1;
}

// setup: 145 blocks x 256. Per-block sniff; block 0 publishes flags;
// idx<34944 prep; idx in [34944,36992) zeros segsum/segkv.
__global__ __launch_bounds__(256) void setup_kernel(
    const void* x, const void* tw, const void* alpha, const void* beta,
    const void* gamma, const void* Wk, const void* bk, const void* Wv,
    const void* bv, const void* Wr, const void* br, const void* Wo,
    const void* bo,
    int n0, int n1, int n2, int n3, int n4, int n5, int n6, int n7,
    int n8, int n9, int n10, int n11, int n12,
    int* __restrict__ flags,
    float* __restrict__ WT4, float* __restrict__ biasWS,
    float* __restrict__ WoF, float* __restrict__ boF,
    float* __restrict__ gammaF, float* __restrict__ segzero)
{
    __shared__ int sf[16];
    int tid = threadIdx.x;
    const void* ps[13] = {x,tw,alpha,beta,gamma,Wk,bk,Wv,bv,Wr,br,Wo,bo};
    int ns[13] = {n0,n1,n2,n3,n4,n5,n6,n7,n8,n9,n10,n11,n12};
    if (tid < 13) sf[tid] = sniff_one((const unsigned short*)ps[tid], ns[tid]);
    __syncthreads();
    if (blockIdx.x == 0 && tid < 14) {
        if (tid == 13) {
            int any16 = 0;
            for (int j = 0; j < 13; ++j) if (sf[j] == 1) any16 = 1;
            flags[13] = any16;
        } else {
            flags[tid] = sf[tid];
        }
    }

    int idx = blockIdx.x * 256 + tid;
    if (idx < 32768) {
        int q = idx >> 8, rem = idx & 255;
        int o = rem >> 2, c = q * 4 + (rem & 3);
        float val = 0.f;
        if (o < 16)      val = ldf(Wk, sf[5], (long)o * 512 + c);
        else if (o < 32) val = ldf(Wv, sf[7], (long)(o - 16) * 512 + c);
        else if (o < 48) val = ldf(Wr, sf[9], (long)(o - 32) * 512 + c);
        WT4[idx] = val;
    } else if (idx < 33792) {
        int i = idx - 32768;
        WoF[i] = ldf(Wo, sf[11], i);
    } else if (idx < 34816) {
        int i = idx - 33792;
        gammaF[i] = ldf(gamma, sf[4], i);
    } else if (idx < 34880) {
        int i = idx - 34816;
        boF[i] = ldf(bo, sf[12], i);
    } else if (idx < 34944) {
        int i = idx - 34880;
        float bb = 0.f;
        if (i < 16)      bb = ldf(bk, sf[6], i);
        else if (i < 32) bb = ldf(bv, sf[8], i - 16);
        else if (i < 48) bb = ldf(br, sf[10], i - 32);
        biasWS[i] = bb;
    } else if (idx < 36992) {
        segzero[idx - 34944] = 0.f;    // segsum[1024] ++ segkv[1024]
    }
}

// proj: 8 rows/block (grid 512), 256 threads = 16 o-quads x 16 c-chunks.
// Writes k_ws, r_ws; atomically accumulates segment sum(k) and sum(k*v).
__global__ __launch_bounds__(256) void proj_kernel(
    const void* __restrict__ x, const float* __restrict__ WT4,
    const float* __restrict__ biasWS, const int* __restrict__ flg,
    float* __restrict__ k_ws, float* __restrict__ r_ws,
    float* __restrict__ segsum, float* __restrict__ segkv)
{
    __shared__ float xs[8 * 512];       // 16 KB
    __shared__ float red[16 * 8 * 64];  // 32 KB
    int tid = threadIdx.x;
    int row0 = blockIdx.x * 8;
    int b = row0 >> 10;
    int lt0 = row0 & 1023;
    int fx = flg[0];

    if (fx == 1) {
        const unsigned short* xp = (const unsigned short*)x;
        #pragma unroll
        for (int j = 0; j < 4; ++j) {
            int v = tid + 256 * j;
            int el = v * 4;
            int r = el >> 9, c = el & 511;
            int lt = lt0 + r - ((c < 256) ? 1 : 0);
            float4 f;
            if (lt < 0) f = make_float4(0.f, 0.f, 0.f, 0.f);
            else {
                const unsigned short* sp = xp + ((long)(b * 1024 + lt) * 512 + c);
                unsigned int u0 = ((unsigned int)sp[0]) << 16;
                unsigned int u1 = ((unsigned int)sp[1]) << 16;
                unsigned int u2 = ((unsigned int)sp[2]) << 16;
                unsigned int u3 = ((unsigned int)sp[3]) << 16;
                __builtin_memcpy(&f.x, &u0, 4); __builtin_memcpy(&f.y, &u1, 4);
                __builtin_memcpy(&f.z, &u2, 4); __builtin_memcpy(&f.w, &u3, 4);
            }
            reinterpret_cast<float4*>(xs)[v] = f;
        }
    } else {
        const float* xp = (const float*)x;
        #pragma unroll
        for (int j = 0; j < 4; ++j) {
            int v = tid + 256 * j;
            int el = v * 4;
            int r = el >> 9, c = el & 511;
            int lt = lt0 + r - ((c < 256) ? 1 : 0);
            float4 f;
            if (lt < 0) f = make_float4(0.f, 0.f, 0.f, 0.f);
            else f = *reinterpret_cast<const float4*>(xp + ((long)(b * 1024 + lt) * 512 + c));
            reinterpret_cast<float4*>(xs)[v] = f;
        }
    }
    __syncthreads();

    int o4 = tid & 15, cc = tid >> 4;
    const float4* xs4 = reinterpret_cast<const float4*>(xs);
    const float4* W4 = reinterpret_cast<const float4*>(WT4);
    float a0[8], a1[8], a2[8], a3[8];
    #pragma unroll
    for (int r = 0; r < 8; ++r) { a0[r] = a1[r] = a2[r] = a3[r] = 0.f; }
    #pragma unroll
    for (int q = 0; q < 8; ++q) {
        int cq = cc * 8 + q;
        float4 w0 = W4[cq * 64 + o4 * 4 + 0];
        float4 w1 = W4[cq * 64 + o4 * 4 + 1];
        float4 w2 = W4[cq * 64 + o4 * 4 + 2];
        float4 w3 = W4[cq * 64 + o4 * 4 + 3];
        #pragma unroll
        for (int r = 0; r < 8; ++r) {
            float4 x4 = xs4[r * 128 + cq];
            a0[r] += x4.x * w0.x + x4.y * w0.y + x4.z * w0.z + x4.w * w0.w;
            a1[r] += x4.x * w1.x + x4.y * w1.y + x4.z * w1.z + x4.w * w1.w;
            a2[r] += x4.x * w2.x + x4.y * w2.y + x4.z * w2.z + x4.w * w2.w;
            a3[r] += x4.x * w3.x + x4.y * w3.y + x4.z * w3.z + x4.w * w3.w;
        }
    }
    float4* red4 = reinterpret_cast<float4*>(red);
    #pragma unroll
    for (int r = 0; r < 8; ++r)
        red4[(cc * 8 + r) * 16 + o4] = make_float4(a0[r], a1[r], a2[r], a3[r]);
    __syncthreads();

    int seg = lt0 >> 6;   // all 8 rows in one 64-t segment (lt0 is 8-aligned)
    #pragma unroll
    for (int it = 0; it < 2; ++it) {
        int idx = tid + 256 * it;        // < 512
        int o2 = idx & 63, r2 = idx >> 6;
        float s = biasWS[o2];
        #pragma unroll
        for (int cc2 = 0; cc2 < 16; ++cc2)
            s += red[(cc2 * 8 + r2) * 64 + o2];
        long a = (long)(lt0 + r2) * 64 + b * 16 + (o2 & 15);
        if (o2 < 16) {
            k_ws[a] = expf(fminf(fmaxf(s, -60.f), 30.f));
        } else if (o2 < 32) {
            int d = o2 - 16;
            float sk = biasWS[d];
            #pragma unroll
            for (int cc2 = 0; cc2 < 16; ++cc2)
                sk += red[(cc2 * 8 + r2) * 64 + d];
            float kk = expf(fminf(fmaxf(sk, -60.f), 30.f));
            atomicAdd(&segsum[seg * 64 + b * 16 + d], kk);
            atomicAdd(&segkv[seg * 64 + b * 16 + d], kk * s);
        } else if (o2 < 48) {
            r_ws[a] = s;
        }
    }
}

// scanB: 16 blocks x 128.
//  tid<64 : cumk in place (exclusive base from segsum) ; blk 0 also kvmean
//  tid>=64: w_sum[u], u = blk*64 + (tid-64)
__global__ __launch_bounds__(128) void scanB_kernel(
    float* k_ws, const float* __restrict__ segsum,
    const float* __restrict__ segkv, float* __restrict__ kvmean,
    const void* __restrict__ tw, const void* __restrict__ alpha,
    const void* __restrict__ beta, const int* __restrict__ flg,
    float* __restrict__ w_sum)
{
    int seg = blockIdx.x, tid = threadIdx.x;
    if (tid < 64) {
        int bd = tid;
        float run = 0.f;
        for (int s = 0; s < seg; ++s) run += segsum[s * 64 + bd];
        for (int i = 0; i < 64; ++i) {
            long a = (long)(seg * 64 + i) * 64 + bd;
            run += k_ws[a];
            k_ws[a] = run;            // in-place cumk (same-thread RAW only)
        }
        if (seg == 0) {
            float kvt = 0.f;
            for (int s = 0; s < 16; ++s) kvt += segkv[s * 64 + bd];
            kvmean[bd] = kvt * (1.0f / 1024.0f);
        }
    } else {
        int u = seg * 64 + (tid - 64);
        int ftw = flg[1], fal = flg[2], fbe = flg[3];
        float acc = 0.f;
        int n = 1024 - u;
        for (int s = 0; s < n; ++s)
            acc += ldf(tw, ftw, 1023 - s) * ldf(beta, fbe, u + s);
        w_sum[u] = acc * ldf(alpha, fal, u);
    }
}

// out: 4 rows/block; rwkv[16] per row via LDS, float4 Wo dots.
__global__ __launch_bounds__(256) void out_kernel(
    const float* __restrict__ r_ws, const float* __restrict__ cumk,
    const float* __restrict__ kvmean, const float* __restrict__ w_sum,
    const float* __restrict__ WoF, const float* __restrict__ boF,
    const float* __restrict__ gammaF, const int* __restrict__ flg,
    void* __restrict__ out)
{
    int tid = threadIdx.x;
    int rl = tid >> 6, o = tid & 63;
    int row = blockIdx.x * 4 + rl;
    int b = row >> 10, t = row & 1023;
    __shared__ float rw[4][16];
    if (o < 16) {
        long a = (long)t * 64 + b * 16 + o;
        rw[rl][o] = r_ws[a] * w_sum[t] * kvmean[b * 16 + o] / (cumk[a] + 1e-8f);
    }
    __syncthreads();
    float acc = boF[o];
    const float4* W4 = reinterpret_cast<const float4*>(WoF + o * 16);
    #pragma unroll
    for (int j = 0; j < 4; ++j) {
        float4 w = W4[j];
        acc += rw[rl][4 * j + 0] * w.x + rw[rl][4 * j + 1] * w.y +
               rw[rl][4 * j + 2] * w.z + rw[rl][4 * j + 3] * w.w;
    }
    float val = acc * gammaF[t];
    if (flg[13]) ((bf16*)out)[(long)row * 64 + o] = __float2bfloat16(val);
    else         ((float*)out)[(long)row * 64 + o] = val;
}

extern "C" void kernel_launch(void* const* d_in, const int* in_sizes, int n_in,
                              void* d_out, int out_size, void* d_ws, size_t ws_size,
                              hipStream_t stream) {
    // insertion order (confirmed R4): x, time_w, time_alpha, time_beta,
    // time_gamma, Wk, bk, Wv, bv, Wr, br, Wo, bo
    const void* x     = d_in[0];
    const void* tw    = d_in[1];
    const void* alpha = d_in[2];
    const void* beta  = d_in[3];
    const void* gamma = d_in[4];
    const void* Wk    = d_in[5];
    const void* bk    = d_in[6];
    const void* Wv    = d_in[7];
    const void* bv    = d_in[8];
    const void* Wr    = d_in[9];
    const void* br    = d_in[10];
    const void* Wo    = d_in[11];
    const void* bo    = d_in[12];

    float* ws     = (float*)d_ws;
    float* k_ws   = ws;             // 65536  [t][bd]; becomes cumk in place
    float* r_ws   = ws + 65536;     // 65536
    float* WT4    = ws + 131072;    // 32768
    float* biasWS = ws + 163840;    // 64
    float* WoF    = ws + 163904;    // 1024
    float* boF    = ws + 164928;    // 64
    float* gammaF = ws + 164992;    // 1024
    float* kvmean = ws + 166016;    // 64
    float* w_sum  = ws + 166080;    // 1024
    float* segsum = ws + 167104;    // 1024  \ zeroed together by setup
    float* segkv  = ws + 168128;    // 1024  /
    int*   flags  = (int*)(ws + 169152);  // 16 ints

    setup_kernel<<<145, 256, 0, stream>>>(
        x, tw, alpha, beta, gamma, Wk, bk, Wv, bv, Wr, br, Wo, bo,
        in_sizes[0], in_sizes[1], in_sizes[2], in_sizes[3], in_sizes[4],
        in_sizes[5], in_sizes[6], in_sizes[7], in_sizes[8], in_sizes[9],
        in_sizes[10], in_sizes[11], in_sizes[12],
        flags, WT4, biasWS, WoF, boF, gammaF, segsum /* ++segkv */);
    proj_kernel<<<512, 256, 0, stream>>>(x, WT4, biasWS, flags,
                                         k_ws, r_ws, segsum, segkv);
    scanB_kernel<<<16, 128, 0, stream>>>(k_ws, segsum, segkv, kvmean,
                                         tw, alpha, beta, flags, w_sum);
    out_kernel<<<1024, 256, 0, stream>>>(r_ws, k_ws, kvmean, w_sum,
                                         WoF, boF, gammaF, flags, (void*)d_out);
}

// Round 10
// 111.764 us; speedup vs baseline: 2.2032x; 2.2032x over previous
//
#include <hip/hip_runtime.h>
#include <hip/hip_bf16.h>

typedef __hip_bfloat16 bf16;

// R10 = R9 structure with the w_sum REGRESSION reverted:
//  R9 post-mortem: scanB computed w_sum[u] with ONE thread per u -> 1024
//  serial dependent L2 loads (~350 cyc/iter) = 151 us. Reverted to R8's
//  parallel strided+tree-reduce wsum inside setup (1024 blocks).
//  Kept from R9: scanA folded into proj via segment atomics; v_ws dead.
// Kernels: setup(1024x256: sniff+prep+wsum+zero segs) -> proj(512x256)
//          -> scanC(16x64: cumk in place + kvmean) -> out(1024x256).
// flags[i]: 0=f32, 1=bf16, 2=all-zero. flags[13] = any bf16 (output dtype).

__device__ __forceinline__ float ldf(const void* p, int f, long idx) {
    if (f == 0) return ((const float*)p)[idx];
    if (f == 1) {
        unsigned int u = ((unsigned int)((const unsigned short*)p)[idx]) << 16;
        float r; __builtin_memcpy(&r, &u, 4); return r;
    }
    return 0.f;
}

__device__ __forceinline__ int sniff_one(const unsigned short* u, int els) {
    int n16 = els < 64 ? els : 64;
    bool allzero = true;
    for (int j = 0; j < n16; ++j) if (u[j] != 0) { allzero = false; break; }
    if (allzero) return 2;
    int npair = n16 / 2;
    for (int j = 0; j < npair; ++j) {
        unsigned short lo = u[2 * j], hi = u[2 * j + 1];
        int elo = (lo >> 7) & 0xFF, ehi = (hi >> 7) & 0xFF;
        bool lo_ok = (elo >= 64 && elo <= 190) || lo == 0;
        bool hi_ok = (ehi >= 64 && ehi <= 190) || hi == 0;
        if (!(lo_ok && hi_ok)) return 0;
    }
    return 1;
}

// setup: grid 1024 x 256.
//  every block : local sniff -> LDS flags; block 0 publishes to global
//  blocks 0-136: prep chunk (WT4/WoF/gammaF/boF/biasWS)
//  blocks 137-144 range: zero segsum/segkv (idx in [34944,36992))
//  every block : w_sum for u = blockIdx.x (256-thread strided + tree reduce)
__global__ __launch_bounds__(256) void setup_kernel(
    const void* x, const void* tw, const void* alpha, const void* beta,
    const void* gamma, const void* Wk, const void* bk, const void* Wv,
    const void* bv, const void* Wr, const void* br, const void* Wo,
    const void* bo,
    int n0, int n1, int n2, int n3, int n4, int n5, int n6, int n7,
    int n8, int n9, int n10, int n11, int n12,
    int* __restrict__ flags,
    float* __restrict__ WT4, float* __restrict__ biasWS,
    float* __restrict__ WoF, float* __restrict__ boF,
    float* __restrict__ gammaF, float* __restrict__ segzero,
    float* __restrict__ w_sum)
{
    __shared__ int sf[16];
    __shared__ float red[256];
    int tid = threadIdx.x;
    const void* ps[13] = {x,tw,alpha,beta,gamma,Wk,bk,Wv,bv,Wr,br,Wo,bo};
    int ns[13] = {n0,n1,n2,n3,n4,n5,n6,n7,n8,n9,n10,n11,n12};
    if (tid < 13) sf[tid] = sniff_one((const unsigned short*)ps[tid], ns[tid]);
    __syncthreads();
    if (blockIdx.x == 0 && tid < 14) {
        if (tid == 13) {
            int any16 = 0;
            for (int j = 0; j < 13; ++j) if (sf[j] == 1) any16 = 1;
            flags[13] = any16;
        } else {
            flags[tid] = sf[tid];
        }
    }

    // ---- prep / zero chunk ----
    int idx = blockIdx.x * 256 + tid;
    if (idx < 32768) {
        int q = idx >> 8, rem = idx & 255;
        int o = rem >> 2, c = q * 4 + (rem & 3);
        float val = 0.f;
        if (o < 16)      val = ldf(Wk, sf[5], (long)o * 512 + c);
        else if (o < 32) val = ldf(Wv, sf[7], (long)(o - 16) * 512 + c);
        else if (o < 48) val = ldf(Wr, sf[9], (long)(o - 32) * 512 + c);
        WT4[idx] = val;
    } else if (idx < 33792) {
        int i = idx - 32768;
        WoF[i] = ldf(Wo, sf[11], i);
    } else if (idx < 34816) {
        int i = idx - 33792;
        gammaF[i] = ldf(gamma, sf[4], i);
    } else if (idx < 34880) {
        int i = idx - 34816;
        boF[i] = ldf(bo, sf[12], i);
    } else if (idx < 34944) {
        int i = idx - 34880;
        float bb = 0.f;
        if (i < 16)      bb = ldf(bk, sf[6], i);
        else if (i < 32) bb = ldf(bv, sf[8], i - 16);
        else if (i < 48) bb = ldf(br, sf[10], i - 32);
        biasWS[i] = bb;
    } else if (idx < 36992) {
        segzero[idx - 34944] = 0.f;    // segsum[1024] ++ segkv[1024]
    }

    // ---- w_sum for u = blockIdx.x (parallel: latency hidden across 256) ----
    int u = blockIdx.x;
    int ftw = sf[1], fal = sf[2], fbe = sf[3];
    float acc = 0.f;
    int n = 1024 - u;
    for (int s = tid; s < n; s += 256)
        acc += ldf(tw, ftw, 1023 - s) * ldf(beta, fbe, u + s);
    red[tid] = acc;
    __syncthreads();
    for (int off = 128; off > 0; off >>= 1) {
        if (tid < off) red[tid] += red[tid + off];
        __syncthreads();
    }
    if (tid == 0) w_sum[u] = red[0] * ldf(alpha, fal, u);
}

// proj: 8 rows/block (grid 512), 256 threads = 16 o-quads x 16 c-chunks.
// Writes k_ws, r_ws; atomically accumulates segment sum(k), sum(k*v).
__global__ __launch_bounds__(256) void proj_kernel(
    const void* __restrict__ x, const float* __restrict__ WT4,
    const float* __restrict__ biasWS, const int* __restrict__ flg,
    float* __restrict__ k_ws, float* __restrict__ r_ws,
    float* __restrict__ segsum, float* __restrict__ segkv)
{
    __shared__ float xs[8 * 512];       // 16 KB
    __shared__ float red[16 * 8 * 64];  // 32 KB
    int tid = threadIdx.x;
    int row0 = blockIdx.x * 8;
    int b = row0 >> 10;
    int lt0 = row0 & 1023;
    int fx = flg[0];

    if (fx == 1) {
        const unsigned short* xp = (const unsigned short*)x;
        #pragma unroll
        for (int j = 0; j < 4; ++j) {
            int v = tid + 256 * j;
            int el = v * 4;
            int r = el >> 9, c = el & 511;
            int lt = lt0 + r - ((c < 256) ? 1 : 0);
            float4 f;
            if (lt < 0) f = make_float4(0.f, 0.f, 0.f, 0.f);
            else {
                const unsigned short* sp = xp + ((long)(b * 1024 + lt) * 512 + c);
                unsigned int u0 = ((unsigned int)sp[0]) << 16;
                unsigned int u1 = ((unsigned int)sp[1]) << 16;
                unsigned int u2 = ((unsigned int)sp[2]) << 16;
                unsigned int u3 = ((unsigned int)sp[3]) << 16;
                __builtin_memcpy(&f.x, &u0, 4); __builtin_memcpy(&f.y, &u1, 4);
                __builtin_memcpy(&f.z, &u2, 4); __builtin_memcpy(&f.w, &u3, 4);
            }
            reinterpret_cast<float4*>(xs)[v] = f;
        }
    } else {
        const float* xp = (const float*)x;
        #pragma unroll
        for (int j = 0; j < 4; ++j) {
            int v = tid + 256 * j;
            int el = v * 4;
            int r = el >> 9, c = el & 511;
            int lt = lt0 + r - ((c < 256) ? 1 : 0);
            float4 f;
            if (lt < 0) f = make_float4(0.f, 0.f, 0.f, 0.f);
            else f = *reinterpret_cast<const float4*>(xp + ((long)(b * 1024 + lt) * 512 + c));
            reinterpret_cast<float4*>(xs)[v] = f;
        }
    }
    __syncthreads();

    int o4 = tid & 15, cc = tid >> 4;
    const float4* xs4 = reinterpret_cast<const float4*>(xs);
    const float4* W4 = reinterpret_cast<const float4*>(WT4);
    float a0[8], a1[8], a2[8], a3[8];
    #pragma unroll
    for (int r = 0; r < 8; ++r) { a0[r] = a1[r] = a2[r] = a3[r] = 0.f; }
    #pragma unroll
    for (int q = 0; q < 8; ++q) {
        int cq = cc * 8 + q;
        float4 w0 = W4[cq * 64 + o4 * 4 + 0];
        float4 w1 = W4[cq * 64 + o4 * 4 + 1];
        float4 w2 = W4[cq * 64 + o4 * 4 + 2];
        float4 w3 = W4[cq * 64 + o4 * 4 + 3];
        #pragma unroll
        for (int r = 0; r < 8; ++r) {
            float4 x4 = xs4[r * 128 + cq];
            a0[r] += x4.x * w0.x + x4.y * w0.y + x4.z * w0.z + x4.w * w0.w;
            a1[r] += x4.x * w1.x + x4.y * w1.y + x4.z * w1.z + x4.w * w1.w;
            a2[r] += x4.x * w2.x + x4.y * w2.y + x4.z * w2.z + x4.w * w2.w;
            a3[r] += x4.x * w3.x + x4.y * w3.y + x4.z * w3.z + x4.w * w3.w;
        }
    }
    float4* red4 = reinterpret_cast<float4*>(red);
    #pragma unroll
    for (int r = 0; r < 8; ++r)
        red4[(cc * 8 + r) * 16 + o4] = make_float4(a0[r], a1[r], a2[r], a3[r]);
    __syncthreads();

    int seg = lt0 >> 6;   // all 8 rows in one 64-t segment (lt0 is 8-aligned)
    #pragma unroll
    for (int it = 0; it < 2; ++it) {
        int idx = tid + 256 * it;        // < 512
        int o2 = idx & 63, r2 = idx >> 6;
        float s = biasWS[o2];
        #pragma unroll
        for (int cc2 = 0; cc2 < 16; ++cc2)
            s += red[(cc2 * 8 + r2) * 64 + o2];
        long a = (long)(lt0 + r2) * 64 + b * 16 + (o2 & 15);
        if (o2 < 16) {
            k_ws[a] = expf(fminf(fmaxf(s, -60.f), 30.f));
        } else if (o2 < 32) {
            int d = o2 - 16;
            float sk = biasWS[d];
            #pragma unroll
            for (int cc2 = 0; cc2 < 16; ++cc2)
                sk += red[(cc2 * 8 + r2) * 64 + d];
            float kk = expf(fminf(fmaxf(sk, -60.f), 30.f));
            atomicAdd(&segsum[seg * 64 + b * 16 + d], kk);
            atomicAdd(&segkv[seg * 64 + b * 16 + d], kk * s);
        } else if (o2 < 48) {
            r_ws[a] = s;
        }
    }
}

// scanC: 16 blocks x 64: cumk in place; block 0 also kvmean.
__global__ __launch_bounds__(64) void scanC_kernel(
    float* k_ws, const float* __restrict__ segsum,
    const float* __restrict__ segkv, float* __restrict__ kvmean)
{
    int seg = blockIdx.x, bd = threadIdx.x;
    float run = 0.f;
    for (int s = 0; s < seg; ++s) run += segsum[s * 64 + bd];
    for (int i = 0; i < 64; ++i) {
        long a = (long)(seg * 64 + i) * 64 + bd;
        run += k_ws[a];
        k_ws[a] = run;            // in-place cumk (same-thread RAW only)
    }
    if (seg == 0) {
        float kvt = 0.f;
        for (int s = 0; s < 16; ++s) kvt += segkv[s * 64 + bd];
        kvmean[bd] = kvt * (1.0f / 1024.0f);
    }
}

// out: 4 rows/block; rwkv[16] per row via LDS, float4 Wo dots.
__global__ __launch_bounds__(256) void out_kernel(
    const float* __restrict__ r_ws, const float* __restrict__ cumk,
    const float* __restrict__ kvmean, const float* __restrict__ w_sum,
    const float* __restrict__ WoF, const float* __restrict__ boF,
    const float* __restrict__ gammaF, const int* __restrict__ flg,
    void* __restrict__ out)
{
    int tid = threadIdx.x;
    int rl = tid >> 6, o = tid & 63;
    int row = blockIdx.x * 4 + rl;
    int b = row >> 10, t = row & 1023;
    __shared__ float rw[4][16];
    if (o < 16) {
        long a = (long)t * 64 + b * 16 + o;
        rw[rl][o] = r_ws[a] * w_sum[t] * kvmean[b * 16 + o] / (cumk[a] + 1e-8f);
    }
    __syncthreads();
    float acc = boF[o];
    const float4* W4 = reinterpret_cast<const float4*>(WoF + o * 16);
    #pragma unroll
    for (int j = 0; j < 4; ++j) {
        float4 w = W4[j];
        acc += rw[rl][4 * j + 0] * w.x + rw[rl][4 * j + 1] * w.y +
               rw[rl][4 * j + 2] * w.z + rw[rl][4 * j + 3] * w.w;
    }
    float val = acc * gammaF[t];
    if (flg[13]) ((bf16*)out)[(long)row * 64 + o] = __float2bfloat16(val);
    else         ((float*)out)[(long)row * 64 + o] = val;
}

extern "C" void kernel_launch(void* const* d_in, const int* in_sizes, int n_in,
                              void* d_out, int out_size, void* d_ws, size_t ws_size,
                              hipStream_t stream) {
    // insertion order (confirmed R4): x, time_w, time_alpha, time_beta,
    // time_gamma, Wk, bk, Wv, bv, Wr, br, Wo, bo
    const void* x     = d_in[0];
    const void* tw    = d_in[1];
    const void* alpha = d_in[2];
    const void* beta  = d_in[3];
    const void* gamma = d_in[4];
    const void* Wk    = d_in[5];
    const void* bk    = d_in[6];
    const void* Wv    = d_in[7];
    const void* bv    = d_in[8];
    const void* Wr    = d_in[9];
    const void* br    = d_in[10];
    const void* Wo    = d_in[11];
    const void* bo    = d_in[12];

    float* ws     = (float*)d_ws;
    float* k_ws   = ws;             // 65536  [t][bd]; becomes cumk in place
    float* r_ws   = ws + 65536;     // 65536
    float* WT4    = ws + 131072;    // 32768
    float* biasWS = ws + 163840;    // 64
    float* WoF    = ws + 163904;    // 1024
    float* boF    = ws + 164928;    // 64
    float* gammaF = ws + 164992;    // 1024
    float* kvmean = ws + 166016;    // 64
    float* w_sum  = ws + 166080;    // 1024
    float* segsum = ws + 167104;    // 1024  \ zeroed together by setup
    float* segkv  = ws + 168128;    // 1024  /
    int*   flags  = (int*)(ws + 169152);  // 16 ints

    setup_kernel<<<1024, 256, 0, stream>>>(
        x, tw, alpha, beta, gamma, Wk, bk, Wv, bv, Wr, br, Wo, bo,
        in_sizes[0], in_sizes[1], in_sizes[2], in_sizes[3], in_sizes[4],
        in_sizes[5], in_sizes[6], in_sizes[7], in_sizes[8], in_sizes[9],
        in_sizes[10], in_sizes[11], in_sizes[12],
        flags, WT4, biasWS, WoF, boF, gammaF, segsum /* ++segkv */, w_sum);
    proj_kernel<<<512, 256, 0, stream>>>(x, WT4, biasWS, flags,
                                         k_ws, r_ws, segsum, segkv);
    scanC_kernel<<<16, 64, 0, stream>>>(k_ws, segsum, segkv, kvmean);
    out_kernel<<<1024, 256, 0, stream>>>(r_ws, k_ws, kvmean, w_sum,
                                         WoF, boF, gammaF, flags, (void*)d_out);
}